// Round 1
// 65.173 us; speedup vs baseline: 1.0225x; 1.0225x over previous
//
#include <hip/hip_runtime.h>

// Active-set water-filling projection, one 64-lane wave per row (B=2048, N=1024).
//
// Monotone-threshold (implicit-mask) reformulation of the reference:
//   phase 0: t is monotone non-increasing -> alive set == {y >= -t}. No mask bits.
//   phase 1: t is monotone non-decreasing -> hi set == {t > u - y}, with the
//            phase-0 lows frozen by encoding them as (u=0, r=-INF), i.e.
//            "clamped at an upper bound of 0". They then contribute 0 to the
//            water-fill sums and output 0, with no extra tests anywhere.
//
// Round r: sums over masks(t_{r-1}) -> reduce -> t_r; a per-lane vote detects
// "no new violators between t_{r-1} and t_r", which is exactly the reference's
// phase-advance condition (the reference's next iteration recomputes an
// identical t from unchanged state, so fusing is bit-equivalent). The final t
// is the last reduction (state unchanged after the terminating vote).
//
// Every per-lane quantity is a NAMED SCALAR: no arrays, no address-taking,
// nothing the compiler could demote to scratch (rule-#20 hazard in the prior
// version's reinterpret_cast<float*>(&yv[j]) idiom).

#define N_COLS 1024
#define NBIKES 512.0f

// x += dpp_moved(x) for two independent accumulators (ILP-paired chains).
#define DPP_ADD2(ctrl)                                                                              \
    a += __int_as_float(__builtin_amdgcn_update_dpp(0, __float_as_int(a), (ctrl), 0xf, 0xf, true)); \
    b += __int_as_float(__builtin_amdgcn_update_dpp(0, __float_as_int(b), (ctrl), 0xf, 0xf, true));

// Full 64-lane sum of a and b; result broadcast to all lanes via readlane.
__device__ __forceinline__ void wave_sum2(float& a, float& b) {
    DPP_ADD2(0x111)   // row_shr:1
    DPP_ADD2(0x112)   // row_shr:2
    DPP_ADD2(0x114)   // row_shr:4
    DPP_ADD2(0x118)   // row_shr:8  -> lanes 15/31/47/63 hold row-of-16 sums
    DPP_ADD2(0x142)   // row_bcast:15
    DPP_ADD2(0x143)   // row_bcast:31 -> lane 63 = full wave sum
    a = __int_as_float(__builtin_amdgcn_readlane(__float_as_int(a), 63));
    b = __int_as_float(__builtin_amdgcn_readlane(__float_as_int(b), 63));
}

#define FOREACH16(OP) OP(0) OP(1) OP(2) OP(3) OP(4) OP(5) OP(6) OP(7) \
                      OP(8) OP(9) OP(10) OP(11) OP(12) OP(13) OP(14) OP(15)

__global__ __launch_bounds__(256) void proj_rows(
    const float* __restrict__ y,
    const float* __restrict__ upper,
    float* __restrict__ out,
    int B)
{
    const int lane = threadIdx.x & 63;
    const int wave = threadIdx.x >> 6;
    const int row  = (blockIdx.x << 2) + wave;
    if (row >= B) return;

    const float* yrow = y + (size_t)row * N_COLS;
    const int col = lane << 2;

    // Each lane owns 16 elements: element = j*256 + 4*lane + k  (j,k in 0..3).
    const float4 Y0 = *reinterpret_cast<const float4*>(yrow + col);
    const float4 Y1 = *reinterpret_cast<const float4*>(yrow + 256 + col);
    const float4 Y2 = *reinterpret_cast<const float4*>(yrow + 512 + col);
    const float4 Y3 = *reinterpret_cast<const float4*>(yrow + 768 + col);
    const float4 U0 = *reinterpret_cast<const float4*>(upper + col);
    const float4 U1 = *reinterpret_cast<const float4*>(upper + 256 + col);
    const float4 U2 = *reinterpret_cast<const float4*>(upper + 512 + col);
    const float4 U3 = *reinterpret_cast<const float4*>(upper + 768 + col);

    float y0 = Y0.x, y1 = Y0.y, y2  = Y0.z, y3  = Y0.w;
    float y4 = Y1.x, y5 = Y1.y, y6  = Y1.z, y7  = Y1.w;
    float y8 = Y2.x, y9 = Y2.y, y10 = Y2.z, y11 = Y2.w;
    float y12 = Y3.x, y13 = Y3.y, y14 = Y3.z, y15 = Y3.w;
    float u0 = U0.x, u1 = U0.y, u2  = U0.z, u3  = U0.w;
    float u4 = U1.x, u5 = U1.y, u6  = U1.z, u7  = U1.w;
    float u8 = U2.x, u9 = U2.y, u10 = U2.z, u11 = U2.w;
    float u12 = U3.x, u13 = U3.y, u14 = U3.z, u15 = U3.w;

    // r_k = u_k - y_k for phase-1 ("hi" iff t > r_k); dead-low: r=-INF, u=0.
    float r0 = 0.f, r1 = 0.f, r2 = 0.f, r3 = 0.f, r4 = 0.f, r5 = 0.f,
          r6 = 0.f, r7 = 0.f, r8 = 0.f, r9 = 0.f, r10 = 0.f, r11 = 0.f,
          r12 = 0.f, r13 = 0.f, r14 = 0.f, r15 = 0.f;

    float t = 1.0e30f;   // phase-0 threshold state; -t = -1e30 -> all alive in round 0
    int phase = 0;
    bool done = false;

    for (int it = 0; it < 32 && !done; ++it) {
        float a = 0.f, b = 0.f;
        if (phase == 0) {                 // wave-uniform branch
            const float nt = -t;
            // alive == {y >= -t};  a = sum(alive y), b = |alive|
#define P0(i) { const bool c = !(y##i < nt); a += c ? y##i : 0.f; b += c ? 1.f : 0.f; }
            FOREACH16(P0)
            wave_sum2(a, b);
            const float tn  = (NBIKES - a) * __builtin_amdgcn_rcpf(fmaxf(b, 1.f));
            const float ntn = -tn;
            // new lower-violators: alive under t, violating under tn
            bool nv = false;
#define V0(i) nv |= (!(y##i < nt)) && (y##i < ntn);
            FOREACH16(V0)
            t = tn;
            if (!__any((int)nv)) {
                // Fused transition (same t, bit-equivalent to reference):
                // freeze lows at threshold tn, check uppers with tn immediately.
                bool hv = false;
#define FRZ(i) { const bool c = !(y##i < ntn);                 \
                 hv |= c && (y##i + tn > u##i);                \
                 r##i = c ? (u##i - y##i) : -3.0e38f;          \
                 u##i = c ? u##i : 0.f; }
                FOREACH16(FRZ)
                phase = 1;
                if (!__any((int)hv)) done = true;   // no upper violators: t final
            }
        } else {
            // hi == {t > r};  dead-low: r=-INF -> always "hi" with u=0 (contributes 0)
#define P1(i) { const bool h = (t > r##i); a += h ? u##i : y##i; b += h ? 0.f : 1.f; }
            FOREACH16(P1)
            wave_sum2(a, b);
            const float tn = (NBIKES - a) * __builtin_amdgcn_rcpf(fmaxf(b, 1.f));
            // new upper-violators between t and tn (t monotone increasing)
            bool nv = false;
#define V1(i) nv |= (tn > r##i) && !(t > r##i);
            FOREACH16(V1)
            t = tn;
            if (!__any((int)nv)) done = true;       // converged: t final
        }
    }

    // Safety for (unreachable) phase-0 exhaustion: alive -> never hi, dead -> 0.
    if (phase == 0) {
        const float nt = -t;
#define FRZ2(i) { const bool c = !(y##i < nt); r##i = c ? 3.0e38f : -3.0e38f; u##i = c ? u##i : 0.f; }
        FOREACH16(FRZ2)
    }

    // Unified output: out = hi ? u : y + t   (dead-low: hi with u=0 -> 0).
    float* orow = out + (size_t)row * N_COLS;
    float4 O;
    O.x = (t > r0)  ? u0  : y0  + t;
    O.y = (t > r1)  ? u1  : y1  + t;
    O.z = (t > r2)  ? u2  : y2  + t;
    O.w = (t > r3)  ? u3  : y3  + t;
    *reinterpret_cast<float4*>(orow + col) = O;
    O.x = (t > r4)  ? u4  : y4  + t;
    O.y = (t > r5)  ? u5  : y5  + t;
    O.z = (t > r6)  ? u6  : y6  + t;
    O.w = (t > r7)  ? u7  : y7  + t;
    *reinterpret_cast<float4*>(orow + 256 + col) = O;
    O.x = (t > r8)  ? u8  : y8  + t;
    O.y = (t > r9)  ? u9  : y9  + t;
    O.z = (t > r10) ? u10 : y10 + t;
    O.w = (t > r11) ? u11 : y11 + t;
    *reinterpret_cast<float4*>(orow + 512 + col) = O;
    O.x = (t > r12) ? u12 : y12 + t;
    O.y = (t > r13) ? u13 : y13 + t;
    O.z = (t > r14) ? u14 : y14 + t;
    O.w = (t > r15) ? u15 : y15 + t;
    *reinterpret_cast<float4*>(orow + 768 + col) = O;
}

extern "C" void kernel_launch(void* const* d_in, const int* in_sizes, int n_in,
                              void* d_out, int out_size, void* d_ws, size_t ws_size,
                              hipStream_t stream) {
    const float* yv    = (const float*)d_in[0];
    const float* upper = (const float*)d_in[1];
    float* out = (float*)d_out;
    const int B = in_sizes[0] / N_COLS;        // 2048
    const int blocks = (B + 3) >> 2;           // 4 rows (waves) per 256-thread block
    proj_rows<<<blocks, 256, 0, stream>>>(yv, upper, out, B);
}